// Round 7
// baseline (294.727 us; speedup 1.0000x reference)
//
#include <hip/hip_runtime.h>

// ---------------------------------------------------------------------------
// GCN: out = A_norm * relu(A_norm * X * W1 + b1) * W2 + b2
// A_norm = D^-1/2 (A + I) D^-1/2, built from 1.6M random edges + self loops.
//
// Round-7 change: CSR build rebuilt as a bucketed two-hop counting sort.
//   k_bhist  : per-superblock (8192 edges) counts into 782 64-node buckets
//   k_cscan  : per-bucket scan over superblocks -> boff[sb][b], btot[b]
//   k_btot   : exclusive scan of bucket totals -> bucket bases
//   k_part   : LDS partition per superblock; packed (src<<16|d) written
//              bucket-contiguous with coalesced runs (~10 edges)
//   k_deg    : per-bucket 64-counter LDS histogram -> exact deg[d]
//   k_scatter2: per-bucket LDS rank cursors; stores land in an 8KB
//              L2-resident window (sectors fully covered)
// This kills the old 12512-bin k_hist, the 98-deep k_colscan, the pos array,
// and k_scatter's ~51MB of random 32B-sector writebacks.
// ---------------------------------------------------------------------------

#define SCAN_TILE 2048   // 256 threads x 8 elements
#define EPB_LOG 13
#define EPB (1 << EPB_LOG)     // 8192 edges per superblock
#define BW_LOG 6
#define BW (1 << BW_LOG)       // 64 dst nodes per bucket
#define MAXBUCK 1024           // fast path: n <= 65536

typedef __attribute__((ext_vector_type(8))) short bf16x8;
typedef __attribute__((ext_vector_type(4))) float f32x4;

__device__ inline unsigned short f2bf(float f) {
    unsigned int b = __float_as_uint(f);
    unsigned int r = b + 0x7FFFu + ((b >> 16) & 1u);   // round-to-nearest-even
    return (unsigned short)(r >> 16);
}
__device__ inline float bf_lo(unsigned int u) { return __uint_as_float(u << 16); }
__device__ inline float bf_hi(unsigned int u) { return __uint_as_float(u & 0xFFFF0000u); }

__global__ void k_init(const int* __restrict__ edges, int* __restrict__ flag,
                       int* __restrict__ cnt, int n) {
    int i = blockIdx.x * blockDim.x + threadIdx.x;
    if (i < n) cnt[i] = 0;   // needed by the fallback path only; cheap
    if (blockIdx.x == 0 && threadIdx.x < 64) {
        // int64 edges little-endian -> odd 32-bit words all zero (vals < 50000)
        int v = edges[2 * threadIdx.x + 1];
        unsigned long long b = __ballot(v != 0);
        if (threadIdx.x == 0) flag[0] = b ? 1 : 2;   // stride in int32 words
    }
}

// W1 [128][256] fp32 -> W1t [256][128] bf16.
__global__ __launch_bounds__(128) void k_prep_w(const float* __restrict__ W1,
        unsigned short* __restrict__ w1t) {
    int n = blockIdx.x;          // 0..255
    int k = threadIdx.x;         // 0..127
    w1t[n * 128 + k] = f2bf(W1[k * 256 + n]);
}

// xs = bf16(dis[node] * x) -- runs AFTER the scan produced dis.
__global__ __launch_bounds__(256) void k_prep_xs(const float* __restrict__ x,
        const float* __restrict__ dis, unsigned short* __restrict__ xs, int n) {
    int i = blockIdx.x * 256 + threadIdx.x;      // over n*32 float4 groups
    if (i >= n * 32) return;
    float dsc = dis[i >> 5];
    float4 v = ((const float4*)x)[i];
    ushort4 o;
    o.x = f2bf(v.x * dsc); o.y = f2bf(v.y * dsc);
    o.z = f2bf(v.z * dsc); o.w = f2bf(v.w * dsc);
    ((ushort4*)xs)[i] = o;
}

// Per-superblock bucket counts: bcnt[sb][b] = #edges in sb with dst in bucket b.
__global__ __launch_bounds__(256) void k_bhist(
        const int* __restrict__ edges, const int* __restrict__ flag,
        int* __restrict__ bcnt, long long E, int nbuck) {
    __shared__ int bins[MAXBUCK];
    int sb = blockIdx.x, t = threadIdx.x;
    for (int i = t; i < nbuck; i += 256) bins[i] = 0;
    __syncthreads();
    int stride = flag[0];
    long long base = (long long)sb << EPB_LOG;
    long long rem = E - base;
    int nE = (rem < (long long)EPB) ? (int)rem : EPB;
    for (int i = t; i < nE; i += 256) {
        int d = edges[(E + base + i) * stride];
        atomicAdd(&bins[d >> BW_LOG], 1);
    }
    __syncthreads();
    for (int i = t; i < nbuck; i += 256) bcnt[(size_t)sb * nbuck + i] = bins[i];
}

// Per-bucket scan over superblocks: bcnt -> exclusive offsets; btot[b] = total.
__global__ void k_cscan(int* __restrict__ bcnt, int* __restrict__ btot,
                        int nsb, int nbuck) {
    int b = blockIdx.x * 256 + threadIdx.x;
    if (b >= nbuck) return;
    int run = 0;
    size_t idx = b;
    for (int s = 0; s < nsb; ++s, idx += nbuck) {
        int v = bcnt[idx];
        bcnt[idx] = run;
        run += v;
    }
    btot[b] = run;
}

// Exclusive scan of <=1024 bucket totals in place (one block).
__global__ __launch_bounds__(256) void k_btot(int* __restrict__ btot, int nbuck) {
    __shared__ int ws4[4];
    int t = threadIdx.x;
    int c4 = (nbuck + 255) >> 8;     // <=4
    int lo = t * c4;
    int hi = lo + c4; if (hi > nbuck) hi = nbuck;
    if (lo > nbuck) lo = nbuck;
    int vals[4];
    int local = 0;
    for (int i = lo; i < hi; ++i) { vals[i - lo] = btot[i]; local += vals[i - lo]; }
    int lane = t & 63, w = t >> 6;
    int inc = local;
    for (int off = 1; off < 64; off <<= 1) {
        int u = __shfl_up(inc, off, 64);
        if (lane >= off) inc += u;
    }
    if (lane == 63) ws4[w] = inc;
    __syncthreads();
    int woff = 0;
    for (int i = 0; i < w; ++i) woff += ws4[i];
    int ex = woff + inc - local;
    for (int i = lo; i < hi; ++i) { btot[i] = ex; ex += vals[i - lo]; }
}

// Partition superblock's edges into bucket-contiguous packed stream.
__global__ __launch_bounds__(256) void k_part(
        const int* __restrict__ edges, const int* __restrict__ flag,
        const int* __restrict__ boff, const int* __restrict__ btot,
        unsigned int* __restrict__ part, long long E, int nbuck) {
    __shared__ unsigned int stage[EPB];   // 32 KB
    __shared__ int bins[MAXBUCK];
    __shared__ int cur[MAXBUCK];
    __shared__ int ws4[4];
    int sb = blockIdx.x, t = threadIdx.x;
    int stride = flag[0];
    long long base = (long long)sb << EPB_LOG;
    long long rem = E - base;
    int nE = (rem < (long long)EPB) ? (int)rem : EPB;
    for (int i = t; i < nbuck; i += 256) bins[i] = 0;
    __syncthreads();
    for (int i = t; i < nE; i += 256) {
        int d = edges[(E + base + i) * stride];
        atomicAdd(&bins[d >> BW_LOG], 1);
    }
    __syncthreads();
    // exclusive scan of bins[0..nbuck) in LDS
    int c4 = (nbuck + 255) >> 8;
    int lo = t * c4;
    int hi = lo + c4; if (hi > nbuck) hi = nbuck;
    if (lo > nbuck) lo = nbuck;
    int local = 0;
    for (int i = lo; i < hi; ++i) local += bins[i];
    int lane = t & 63, w = t >> 6;
    int inc = local;
    for (int off = 1; off < 64; off <<= 1) {
        int u = __shfl_up(inc, off, 64);
        if (lane >= off) inc += u;
    }
    if (lane == 63) ws4[w] = inc;
    __syncthreads();
    int woff = 0;
    for (int i = 0; i < w; ++i) woff += ws4[i];
    int ex = woff + inc - local;
    for (int i = lo; i < hi; ++i) {
        int v = bins[i];
        bins[i] = ex;         // local exclusive offset (kept for flush)
        cur[i] = ex;          // running cursor
        ex += v;
    }
    __syncthreads();
    // place pass
    for (int i = t; i < nE; i += 256) {
        int s = edges[(base + i) * stride];
        int d = edges[(E + base + i) * stride];
        int b = d >> BW_LOG;
        int p = atomicAdd(&cur[b], 1);
        stage[p] = ((unsigned int)s << 16) | (unsigned int)d;
    }
    __syncthreads();
    // flush: consecutive i -> runs in the same bucket -> coalesced global writes
    for (int i = t; i < nE; i += 256) {
        unsigned int pk = stage[i];
        int b = (int)(pk & 0xFFFFu) >> BW_LOG;
        int g = btot[b] + boff[(size_t)sb * nbuck + b] + (i - bins[b]);
        part[g] = pk;
    }
}

// Exact per-node degree from the bucketed stream (64 LDS counters per block).
__global__ __launch_bounds__(256) void k_deg(
        const unsigned int* __restrict__ part, const int* __restrict__ btot,
        int* __restrict__ deg, int nbuck, int n, long long E) {
    __shared__ int c64[BW];
    int b = blockIdx.x, t = threadIdx.x;
    if (t < BW) c64[t] = 0;
    __syncthreads();
    int start = btot[b];
    int endp = (b + 1 < nbuck) ? btot[b + 1] : (int)E;
    for (int i = start + t; i < endp; i += 256)
        atomicAdd(&c64[part[i] & (BW - 1)], 1);
    __syncthreads();
    if (t < BW) {
        int d = (b << BW_LOG) + t;
        if (d < n) deg[d] = c64[t];
    }
}

// Per-block sums of cnt (8 elems/thread).
__global__ __launch_bounds__(256) void k_scan_partial(
        const int* __restrict__ cnt, int* __restrict__ bsum, int n) {
    int t = threadIdx.x;
    int idx = blockIdx.x * SCAN_TILE + t * 8;
    int s = 0;
#pragma unroll
    for (int j = 0; j < 8; ++j) {
        int i = idx + j;
        if (i < n) s += cnt[i];
    }
    for (int off = 32; off; off >>= 1) s += __shfl_down(s, off, 64);
    __shared__ int ws[4];
    if ((t & 63) == 0) ws[t >> 6] = s;
    __syncthreads();
    if (t == 0) bsum[blockIdx.x] = ws[0] + ws[1] + ws[2] + ws[3];
}

// Exclusive scan of <=64 block sums, in place, one wave.
__global__ void k_scan_tops(int* __restrict__ bsum, int nb) {
    int t = threadIdx.x;
    int w = (t < nb) ? bsum[t] : 0;
    int v = w;
    for (int off = 1; off < 64; off <<= 1) {
        int u = __shfl_up(v, off, 64);
        if (t >= off) v += u;
    }
    if (t < nb) bsum[t] = v - w;   // exclusive
}

// Apply: recompute intra-block prefix, add block offset, emit row_start & dis.
__global__ __launch_bounds__(256) void k_scan_apply(
        const int* __restrict__ cnt, const int* __restrict__ bsum,
        int* __restrict__ row_start, float* __restrict__ dis, int n) {
    int t = threadIdx.x;
    int lane = t & 63, w = t >> 6;
    int idx = blockIdx.x * SCAN_TILE + t * 8;
    int vals[8];
    int s = 0;
#pragma unroll
    for (int j = 0; j < 8; ++j) {
        int i = idx + j;
        vals[j] = (i < n) ? cnt[i] : 0;
        s += vals[j];
    }
    int inc = s;
    for (int off = 1; off < 64; off <<= 1) {
        int u = __shfl_up(inc, off, 64);
        if (lane >= off) inc += u;
    }
    __shared__ int wsum[4];
    if (lane == 63) wsum[w] = inc;
    __syncthreads();
    int woff = 0;
    for (int i = 0; i < w; ++i) woff += wsum[i];
    int ex = bsum[blockIdx.x] + woff + inc - s;  // exclusive prefix of this chunk
#pragma unroll
    for (int j = 0; j < 8; ++j) {
        int i = idx + j;
        if (i < n) {
            row_start[i] = ex;
            dis[i] = rsqrtf((float)vals[j] + 1.0f);  // +1 = self loop
            ex += vals[j];
        }
    }
    if (idx <= n && n < idx + 8) row_start[n] = ex;  // unique thread
}

// Final CSR fill: per bucket, LDS cursors assign within-row ranks; stores land
// in an ~8KB L2-resident window (sectors fully covered -> no amplification).
__global__ __launch_bounds__(256) void k_scatter2(
        const unsigned int* __restrict__ part, const int* __restrict__ btot,
        const int* __restrict__ row_start, int* __restrict__ csr_src,
        int nbuck, long long E) {
    __shared__ int c64[BW];
    int b = blockIdx.x, t = threadIdx.x;
    if (t < BW) c64[t] = 0;
    __syncthreads();
    int start = btot[b];
    int endp = (b + 1 < nbuck) ? btot[b + 1] : (int)E;
    for (int i = start + t; i < endp; i += 256) {
        unsigned int pk = part[i];
        int d = (int)(pk & 0xFFFFu);
        int s = (int)(pk >> 16);
        int r = atomicAdd(&c64[d & (BW - 1)], 1);
        csr_src[row_start[d] + r] = s;
    }
}

// ---- fallback path (only if n >= 65536; never for this problem) ----
__global__ void k_count_slow(const int* __restrict__ edges, const int* __restrict__ flag,
                             int* __restrict__ cnt, int* __restrict__ posi, long long E) {
    long long e = (long long)blockIdx.x * blockDim.x + threadIdx.x;
    if (e >= E) return;
    int stride = flag[0];
    int d = edges[(E + e) * stride];
    posi[e] = atomicAdd(&cnt[d], 1);
}
__global__ void k_scatter_slow(const int* __restrict__ edges, const int* __restrict__ flag,
                               const int* __restrict__ row_start, const int* __restrict__ posi,
                               int* __restrict__ csr_src, long long E) {
    long long e = (long long)blockIdx.x * blockDim.x + threadIdx.x;
    if (e >= E) return;
    int stride = flag[0];
    int s = edges[e * stride];
    int d = edges[(E + e) * stride];
    csr_src[row_start[d] + posi[e]] = s;
}
// ---------------------------------------------------------------------------

// agg_i = dn_i * (sum_e xs[src_e] + xs_i). One wave per node; lane owns one
// uint (2 bf16 features). Per edge: 1 index load + 1 row load + 2 adds.
__global__ __launch_bounds__(256) void k_agg(
        const unsigned short* __restrict__ xs, const int* __restrict__ csr_src,
        const int* __restrict__ row_start, const float* __restrict__ dis,
        unsigned short* __restrict__ aggh, int n) {
    int wid  = (blockIdx.x * blockDim.x + threadIdx.x) >> 6;
    int lane = threadIdx.x & 63;
    if (wid >= n) return;
    int start = row_start[wid], end = row_start[wid + 1];
    unsigned int self = ((const unsigned int*)(xs + (size_t)wid * 128))[lane];
    float acc0 = bf_lo(self);
    float acc1 = bf_hi(self);
    int e = start;
    for (; e + 7 < end; e += 8) {
        int s0 = csr_src[e],     s1 = csr_src[e + 1];
        int s2 = csr_src[e + 2], s3 = csr_src[e + 3];
        int s4 = csr_src[e + 4], s5 = csr_src[e + 5];
        int s6 = csr_src[e + 6], s7 = csr_src[e + 7];
        unsigned int v0 = ((const unsigned int*)(xs + (size_t)s0 * 128))[lane];
        unsigned int v1 = ((const unsigned int*)(xs + (size_t)s1 * 128))[lane];
        unsigned int v2 = ((const unsigned int*)(xs + (size_t)s2 * 128))[lane];
        unsigned int v3 = ((const unsigned int*)(xs + (size_t)s3 * 128))[lane];
        unsigned int v4 = ((const unsigned int*)(xs + (size_t)s4 * 128))[lane];
        unsigned int v5 = ((const unsigned int*)(xs + (size_t)s5 * 128))[lane];
        unsigned int v6 = ((const unsigned int*)(xs + (size_t)s6 * 128))[lane];
        unsigned int v7 = ((const unsigned int*)(xs + (size_t)s7 * 128))[lane];
        acc0 += bf_lo(v0); acc1 += bf_hi(v0);
        acc0 += bf_lo(v1); acc1 += bf_hi(v1);
        acc0 += bf_lo(v2); acc1 += bf_hi(v2);
        acc0 += bf_lo(v3); acc1 += bf_hi(v3);
        acc0 += bf_lo(v4); acc1 += bf_hi(v4);
        acc0 += bf_lo(v5); acc1 += bf_hi(v5);
        acc0 += bf_lo(v6); acc1 += bf_hi(v6);
        acc0 += bf_lo(v7); acc1 += bf_hi(v7);
    }
    for (; e < end; ++e) {
        int s0 = csr_src[e];
        unsigned int v0 = ((const unsigned int*)(xs + (size_t)s0 * 128))[lane];
        acc0 += bf_lo(v0); acc1 += bf_hi(v0);
    }
    float dn = dis[wid];
    unsigned int pack = (unsigned int)f2bf(acc0 * dn) | ((unsigned int)f2bf(acc1 * dn) << 16);
    ((unsigned int*)(aggh + (size_t)wid * 128))[lane] = pack;
}

// MFMA GEMM: svs = dis * (relu(agg @ W1 + b1) @ W2).
__global__ __launch_bounds__(256) void k_mm(
        const unsigned short* __restrict__ aggh, const unsigned short* __restrict__ w1t,
        const float* __restrict__ b1, const float* __restrict__ W2,
        const float* __restrict__ dis, float* __restrict__ svs, int n) {
    int wave = threadIdx.x >> 6;        // 0..3
    int lane = threadIdx.x & 63;
    int m    = lane & 15;
    int quad = lane >> 4;               // 0..3
    int node0 = blockIdx.x * 64 + wave * 16;

    bf16x8 afrag[4];
    const unsigned short* arow = aggh + (size_t)(node0 + m) * 128 + quad * 8;
#pragma unroll
    for (int ks = 0; ks < 4; ++ks)
        afrag[ks] = *(const bf16x8*)(arow + ks * 32);

    float p0 = 0.f, p1 = 0.f, p2 = 0.f, p3 = 0.f;
#pragma unroll 1
    for (int t = 0; t < 16; ++t) {
        const unsigned short* brow = w1t + (size_t)(t * 16 + m) * 128 + quad * 8;
        f32x4 acc = {0.f, 0.f, 0.f, 0.f};
#pragma unroll
        for (int ks = 0; ks < 4; ++ks) {
            bf16x8 bfrag = *(const bf16x8*)(brow + ks * 32);
            acc = __builtin_amdgcn_mfma_f32_16x16x32_bf16(afrag[ks], bfrag, acc, 0, 0, 0);
        }
        int col = t * 16 + m;
        float bb = b1[col], w2 = W2[col];
        float h0 = acc[0] + bb, h1 = acc[1] + bb, h2 = acc[2] + bb, h3 = acc[3] + bb;
        p0 += (h0 > 0.f ? h0 : 0.f) * w2;
        p1 += (h1 > 0.f ? h1 : 0.f) * w2;
        p2 += (h2 > 0.f ? h2 : 0.f) * w2;
        p3 += (h3 > 0.f ? h3 : 0.f) * w2;
    }
#pragma unroll
    for (int off = 1; off < 16; off <<= 1) {
        p0 += __shfl_xor(p0, off, 64);
        p1 += __shfl_xor(p1, off, 64);
        p2 += __shfl_xor(p2, off, 64);
        p3 += __shfl_xor(p3, off, 64);
    }
    if (m == 0) {
        int nb = node0 + quad * 4;
        if (nb + 0 < n) svs[nb + 0] = p0 * dis[nb + 0];
        if (nb + 1 < n) svs[nb + 1] = p1 * dis[nb + 1];
        if (nb + 2 < n) svs[nb + 2] = p2 * dis[nb + 2];
        if (nb + 3 < n) svs[nb + 3] = p3 * dis[nb + 3];
    }
}

// out[i] = b2 + dn_i * (sum_e svs[src_e] + svs[i]); wave per node.
__global__ __launch_bounds__(256) void k_out(
        const float* __restrict__ svs, const int* __restrict__ csr_src,
        const int* __restrict__ row_start, const float* __restrict__ dis,
        const float* __restrict__ b2, float* __restrict__ out, int n) {
    int wid  = (blockIdx.x * blockDim.x + threadIdx.x) >> 6;
    int lane = threadIdx.x & 63;
    if (wid >= n) return;
    int start = row_start[wid], end = row_start[wid + 1];
    float acc = 0.f;
    for (int e = start + lane; e < end; e += 64)
        acc += svs[csr_src[e]];
    for (int off = 32; off; off >>= 1) acc += __shfl_down(acc, off, 64);
    if (lane == 0)
        out[wid] = dis[wid] * (acc + svs[wid]) + b2[0];
}

extern "C" void kernel_launch(void* const* d_in, const int* in_sizes, int n_in,
                              void* d_out, int out_size, void* d_ws, size_t ws_size,
                              hipStream_t stream) {
    const float* x  = (const float*)d_in[0];
    const int*   ei = (const int*)d_in[1];
    const float* W1 = (const float*)d_in[2];
    const float* b1 = (const float*)d_in[3];
    const float* W2 = (const float*)d_in[4];
    const float* b2 = (const float*)d_in[5];
    float* out = (float*)d_out;

    const int N = in_sizes[0] / 128;
    const long long E = in_sizes[1] / 2;
    const int nsb = (int)((E + EPB - 1) >> EPB_LOG);   // superblocks (196)
    const int nbuck = (N + BW - 1) >> BW_LOG;          // 782 for N=50000

    char* ws = (char*)d_ws;
    size_t off = 0;
    auto take = [&](size_t bytes) -> char* {
        char* p = ws + off;
        off = (off + bytes + 255) & ~(size_t)255;
        return p;
    };
    int*            flag    = (int*)take(4);
    int*            cnt     = (int*)take((size_t)N * 4);
    int*            rs      = (int*)take((size_t)(N + 1) * 4);
    float*          dis     = (float*)take((size_t)N * 4);
    float*          svs     = (float*)take((size_t)N * 4);
    int*            bsum    = (int*)take(64 * 4);
    int*            btot    = (int*)take((size_t)(nbuck + 1) * 4);
    int*            bcnt    = (int*)take((size_t)nsb * nbuck * 4);
    unsigned int*   part    = (unsigned int*)take((size_t)E * 4);  // packed / posi slow
    int*            csr_src = (int*)take((size_t)E * 4);
    unsigned short* xs      = (unsigned short*)take((size_t)N * 128 * 2);
    unsigned short* w1t     = (unsigned short*)take((size_t)256 * 128 * 2);
    unsigned short* aggh    = (unsigned short*)take((size_t)(N + 64) * 128 * 2);

    int nb_n  = (N + 255) / 256;
    int nb_e  = (int)((E + 255) / 256);
    int nb_s  = (N + SCAN_TILE - 1) / SCAN_TILE;   // 25 for N=50000
    int nb_x  = (N * 32 + 255) / 256;
    int nb_mm = (N + 63) / 64;
    int nb_cs = (nbuck + 255) / 256;

    bool fast = (N < 65536);   // packed (src<<16|d) and nbuck<=1024

    k_init   <<<nb_n, 256, 0, stream>>>(ei, flag, cnt, N);
    k_prep_w <<<256, 128, 0, stream>>>(W1, w1t);
    if (fast) {
        k_bhist   <<<nsb, 256, 0, stream>>>(ei, flag, bcnt, E, nbuck);
        k_cscan   <<<nb_cs, 256, 0, stream>>>(bcnt, btot, nsb, nbuck);
        k_btot    <<<1, 256, 0, stream>>>(btot, nbuck);
        k_part    <<<nsb, 256, 0, stream>>>(ei, flag, bcnt, btot, part, E, nbuck);
        k_deg     <<<nbuck, 256, 0, stream>>>(part, btot, cnt, nbuck, N, E);
    } else {
        k_count_slow<<<nb_e, 256, 0, stream>>>(ei, flag, cnt, (int*)part, E);
    }
    k_scan_partial<<<nb_s, 256, 0, stream>>>(cnt, bsum, N);
    k_scan_tops   <<<1, 64, 0, stream>>>(bsum, nb_s);
    k_scan_apply  <<<nb_s, 256, 0, stream>>>(cnt, bsum, rs, dis, N);
    k_prep_xs     <<<nb_x, 256, 0, stream>>>(x, dis, xs, N);
    if (fast) {
        k_scatter2<<<nbuck, 256, 0, stream>>>(part, btot, rs, csr_src, nbuck, E);
    } else {
        k_scatter_slow<<<nb_e, 256, 0, stream>>>(ei, flag, rs, (const int*)part, csr_src, E);
    }
    k_agg<<<(N + 3) / 4, 256, 0, stream>>>(xs, csr_src, rs, dis, aggh, N);
    k_mm <<<nb_mm, 256, 0, stream>>>(aggh, w1t, b1, W2, dis, svs, N);
    k_out<<<(N + 3) / 4, 256, 0, stream>>>(svs, csr_src, rs, dis, b2, out, N);
}